// Round 1
// 264.416 us; speedup vs baseline: 1.0133x; 1.0133x over previous
//
#include <hip/hip_runtime.h>
#include <math.h>

typedef unsigned short u16;
typedef __attribute__((ext_vector_type(8))) short short8;
typedef __attribute__((ext_vector_type(4))) float f32x4;
typedef __attribute__((ext_vector_type(4))) unsigned short u16x4;
typedef __attribute__((ext_vector_type(8))) unsigned short u16x8;

#define N_TOK 2048
#define DIM 1024
#define OUT_ELEMS 2097152   // N_TOK * DIM

#define GLDS16(gp, lp) __builtin_amdgcn_global_load_lds( \
    (const __attribute__((address_space(1))) unsigned int*)(gp), \
    (__attribute__((address_space(3))) unsigned int*)(lp), 16, 0, 0)

__device__ __forceinline__ u16 f2bf(float f) {
    union { float f; unsigned u; } v; v.f = f;
    unsigned r = (v.u + 0x7FFFu + ((v.u >> 16) & 1u)) >> 16;
    return (u16)r;
}
__device__ __forceinline__ float bf2f(u16 h) {
    union { unsigned u; float f; } v; v.u = ((unsigned)h) << 16;
    return v.f;
}

// ---- cvt of one 8-row k-chunk: fp32 [8][1024] -> bf16 W'[n][8k] (16KB) ----
// Async GLDS16 staging (no VGPR round-trip -> loads fully pipelined), then
// conflict-free ds_read_b128 transpose-convert, contiguous 16B stores.
__device__ __forceinline__ void cvt_chunk(const float* __restrict__ src,
                                          u16* __restrict__ dst, int chunk,
                                          char* smem, int t) {
    float* tile = (float*)smem;                          // [8][1024] f32 = 32KB
    const char* gsrc = (const char*)(src + (size_t)chunk * 8192);
    u16* dchunk = dst + (size_t)chunk * 8192;            // 16KB contiguous out
    int w = t >> 6, l = t & 63;
#pragma unroll
    for (int j = 0; j < 8; j++) {
        int idx = w * 8 + j;                             // 1KB unit, 0..31
        GLDS16(gsrc + idx * 1024 + l * 16, smem + idx * 1024);
    }
    __syncthreads();                                     // drains vmcnt before barrier
    int n0 = (t & 63) * 4 + (t >> 6) * 256;              // 4 consecutive n per thread
    f32x4 v[8];
#pragma unroll
    for (int k = 0; k < 8; k++)
        v[k] = *(const f32x4*)(tile + k * 1024 + n0);    // bank = n%32: conflict-free
#pragma unroll
    for (int i = 0; i < 4; i++) {
        u16x8 o;
#pragma unroll
        for (int k = 0; k < 8; k++) o[k] = f2bf(v[k][i]);
        *(u16x8*)(dchunk + (size_t)(n0 + i) * 8) = o;    // 16B aligned, coalesced
    }
}

// ---------------- k_front: cvt(gate/up, 18 mats) + router, one launch -------
__global__ __launch_bounds__(256)
void k_front(const float* __restrict__ wg, const float* __restrict__ wu,
             const float* __restrict__ wsg, const float* __restrict__ wsu,
             u16* __restrict__ wgt, u16* __restrict__ wut,
             u16* __restrict__ wsgt, u16* __restrict__ wsut,
             const float* __restrict__ x, const float* __restrict__ wgate,
             u16* __restrict__ xb, int* __restrict__ tidx, float* __restrict__ tw,
             float* __restrict__ Pp, int* __restrict__ Cp,
             int* __restrict__ tlist, int* __restrict__ curs) {
    __shared__ __attribute__((aligned(128))) char smem[32768];
    int bx = blockIdx.x;
    int t = threadIdx.x;
    if (bx < 2304) {                                     // ---- cvt role ----
        int mat = bx >> 7, chunk = bx & 127;
        const float* src; u16* dst;
        if      (mat <  8) { src = wg + (size_t)mat * 1048576;       dst = wgt + (size_t)mat * 1048576; }
        else if (mat < 16) { src = wu + (size_t)(mat - 8) * 1048576; dst = wut + (size_t)(mat - 8) * 1048576; }
        else if (mat == 16){ src = wsg; dst = wsgt; }
        else               { src = wsu; dst = wsut; }
        cvt_chunk(src, dst, chunk, smem, t);
        return;
    }
    // ---- router role: block b handles tokens 4b..4b+3, one per wave ----
    int b = bx - 2304;                                   // 0..511
    float* sP = (float*)smem;
    int*   sC = (int*)(smem + 64);
    if (t < 8) { sP[t] = 0.f; sC[t] = 0; }
    if (b == 0 && t < 16) curs[t] = 0;                   // safe: scatter runs next launch
    __syncthreads();
    int wave = t >> 6;
    int lane = t & 63;
    int n = b * 4 + wave;
    const float* xr = x + (size_t)n * DIM;
    u16* xbr = xb + (size_t)n * DIM;
    float acc[8] = {0.f,0.f,0.f,0.f,0.f,0.f,0.f,0.f};
#pragma unroll
    for (int i = 0; i < 16; i++) {
        int d = lane + i * 64;
        float xv = xr[d];
        xbr[d] = f2bf(xv);
        const float* wr = wgate + d * 8;
#pragma unroll
        for (int e = 0; e < 8; e++) acc[e] += xv * wr[e];
    }
#pragma unroll
    for (int off = 32; off; off >>= 1) {
#pragma unroll
        for (int e = 0; e < 8; e++) acc[e] += __shfl_xor(acc[e], off);
    }
    if (lane == 0) {
        tlist[4096 + n] = n;                             // shared-expert token list
        float mx = acc[0];
#pragma unroll
        for (int e = 1; e < 8; e++) mx = fmaxf(mx, acc[e]);
        float p[8], s = 0.f;
#pragma unroll
        for (int e = 0; e < 8; e++) { p[e] = expf(acc[e] - mx); s += p[e]; }
        float inv = 1.f / s;
#pragma unroll
        for (int e = 0; e < 8; e++) atomicAdd(&sP[e], p[e] * inv);
        int i0 = 0; float b0 = acc[0];
#pragma unroll
        for (int e = 1; e < 8; e++) if (acc[e] > b0) { b0 = acc[e]; i0 = e; }
        int i1 = -1; float b1 = -3.4e38f;
#pragma unroll
        for (int e = 0; e < 8; e++) if (e != i0 && acc[e] > b1) { b1 = acc[e]; i1 = e; }
        float w0 = 1.f / (1.f + expf(b1 - b0));
        tidx[n * 2] = i0; tidx[n * 2 + 1] = i1;
        tw[n * 2] = w0;   tw[n * 2 + 1] = 1.f - w0;
        atomicAdd(&sC[i0], 1);
        atomicAdd(&sC[i1], 1);
    }
    __syncthreads();
    if (t < 8) { Pp[b * 8 + t] = sP[t]; Cp[b * 8 + t] = sC[t]; }   // per-block partials
}

// -------- scatter: reduce partials, aux loss, offs, slot assignment ---------
__global__ void k_scatter(const int* __restrict__ tidx, const float* __restrict__ Pp,
                          const int* __restrict__ Cp, int* __restrict__ curs,
                          int* __restrict__ tlist, int* __restrict__ slots,
                          float* __restrict__ out, int* __restrict__ counts,
                          int* __restrict__ offs) {
    __shared__ int   s_off[8];
    __shared__ int   sCnt[8];
    __shared__ float sPs[8];
    __shared__ int   redC[256];
    __shared__ float redP[256];
    int t = threadIdx.x;
    int e = t & 7, g = t >> 3;                           // 32 groups per expert
    int cs = 0; float ps = 0.f;
#pragma unroll
    for (int j = 0; j < 16; j++) {
        int b = g + j * 32;
        cs += Cp[b * 8 + e];
        ps += Pp[b * 8 + e];
    }
    redC[t] = cs; redP[t] = ps;
    __syncthreads();
    if (t < 8) {
        int c = 0; float p = 0.f;
        for (int g2 = 0; g2 < 32; g2++) { c += redC[g2 * 8 + t]; p += redP[g2 * 8 + t]; }
        sCnt[t] = c; sPs[t] = p;
    }
    __syncthreads();
    if (t == 0) {
        int o = 0;
        for (int e2 = 0; e2 < 8; e2++) { s_off[e2] = o; o += sCnt[e2]; }
    }
    __syncthreads();
    if (blockIdx.x == 0 && t == 0) {
        float aux = 0.f;
        for (int e2 = 0; e2 < 8; e2++) {
            aux += (float)sCnt[e2] * sPs[e2];
            offs[e2] = s_off[e2]; counts[e2] = sCnt[e2];
        }
        out[OUT_ELEMS] = 8.f * aux / ((float)N_TOK * (float)N_TOK);
        offs[8] = 4096; counts[8] = 2048;
    }
    int n = blockIdx.x * 256 + t;
    if (n < N_TOK) {
#pragma unroll
        for (int k = 0; k < 2; k++) {
            int ee = tidx[n * 2 + k];
            int p = atomicAdd(&curs[ee], 1);
            int sl = s_off[ee] + p;
            tlist[sl] = n;
            slots[n * 2 + k] = sl;
        }
    }
}

// -------- GEMM1 (+fused cvt of down matrices on otherwise-idle CUs) ---------
__global__ __launch_bounds__(256, 2)
void k_gemm1(const u16* __restrict__ xb, const u16* __restrict__ wgt,
             const u16* __restrict__ wut, const u16* __restrict__ wsgt,
             const u16* __restrict__ wsut, const int* __restrict__ tlist,
             const int* __restrict__ counts, const int* __restrict__ offs,
             u16* __restrict__ H,
             const float* __restrict__ wd, const float* __restrict__ wsd,
             u16* __restrict__ wdt, u16* __restrict__ wsdt) {
    __shared__ __attribute__((aligned(128))) char smem[32768];
    int bx = blockIdx.x;
    int t = threadIdx.x;
    if (bx < 1152) {                                     // ---- cvt_d role ----
        int mat = bx >> 7, chunk = bx & 127;
        const float* src = (mat < 8) ? (wd + (size_t)mat * 1048576) : wsd;
        u16* dst = (mat < 8) ? (wdt + (size_t)mat * 1048576) : wsdt;
        cvt_chunk(src, dst, chunk, smem, t);
        return;
    }
    int bg = bx - 1152;
    int job = bg >> 7;
    int mt = (bg >> 3) & 15;
    int nt = bg & 7;
    int jcnt = counts[job];
    int m0 = mt << 7;
    if (m0 >= jcnt) return;
    int joff = offs[job];
    int n0 = nt << 7;
    const u16* Bg = (job < 8) ? (wgt + (size_t)job * 1048576) : wsgt;
    const u16* Bu = (job < 8) ? (wut + (size_t)job * 1048576) : wsut;

    u16* As  = (u16*)smem;                               // 8KB
    u16* Bgs = (u16*)(smem + 8192);                      // 8KB
    u16* Bus = (u16*)(smem + 16384);                     // 8KB

    int wave = t >> 6, lane = t & 63;
    int ch = (lane & 3) * 8;
    int r0 = (wave * 2 + 0) * 16 + (lane >> 2);
    int r1 = (wave * 2 + 1) * 16 + (lane >> 2);
    int tok0 = tlist[joff + m0 + r0];
    int tok1 = tlist[joff + m0 + r1];
    const u16* a0 = xb + (size_t)tok0 * 1024 + ch;
    const u16* a1 = xb + (size_t)tok1 * 1024 + ch;
    const u16* gB = Bg + (size_t)wave * 8192 + (size_t)(n0 + lane) * 8;
    const u16* uB = Bu + (size_t)wave * 8192 + (size_t)(n0 + lane) * 8;
    u16* lA0 = As  + (wave * 2 + 0) * 512;  u16* lA1 = As  + (wave * 2 + 1) * 512;
    u16* lGa = Bgs + wave * 1024;           u16* lGb = Bgs + wave * 1024 + 512;
    u16* lUa = Bus + wave * 1024;           u16* lUb = Bus + wave * 1024 + 512;

    int wm = (wave >> 1) << 6, wn = (wave & 1) << 6;
    int quad = lane >> 4, lr = lane & 15;

    f32x4 accg[4][4], accu[4][4];
    f32x4 zz = {0.f, 0.f, 0.f, 0.f};
#pragma unroll
    for (int i = 0; i < 4; i++)
#pragma unroll
        for (int j = 0; j < 4; j++) { accg[i][j] = zz; accu[i][j] = zz; }

    for (int k0 = 0; k0 < 1024; k0 += 32) {
        size_t koff = (size_t)k0 * 1024;
        GLDS16(a0 + k0, lA0);        GLDS16(a1 + k0, lA1);
        GLDS16(gB + koff, lGa);      GLDS16(gB + koff + 512, lGb);
        GLDS16(uB + koff, lUa);      GLDS16(uB + koff + 512, lUb);
        __syncthreads();
        short8 af[4], bgf[4], buf[4];
#pragma unroll
        for (int i = 0; i < 4; i++) {
            int nrow = wn + i * 16 + lr;
            af[i]  = *(const short8*)(As  + (wm + i * 16 + lr) * 32 + quad * 8);
            bgf[i] = *(const short8*)(Bgs + quad * 1024 + nrow * 8);
            buf[i] = *(const short8*)(Bus + quad * 1024 + nrow * 8);
        }
#pragma unroll
        for (int mi = 0; mi < 4; mi++)
#pragma unroll
            for (int ni = 0; ni < 4; ni++) {
                accg[mi][ni] = __builtin_amdgcn_mfma_f32_16x16x32_bf16(af[mi], bgf[ni], accg[mi][ni], 0, 0, 0);
                accu[mi][ni] = __builtin_amdgcn_mfma_f32_16x16x32_bf16(af[mi], buf[ni], accu[mi][ni], 0, 0, 0);
            }
        __syncthreads();
    }
#pragma unroll
    for (int mi = 0; mi < 4; mi++) {
        int rowb = m0 + wm + mi * 16 + quad * 4;
#pragma unroll
        for (int rr = 0; rr < 4; rr++) {
            int row = rowb + rr;
            if (row < jcnt) {
                size_t base = (size_t)(joff + row) * 1024 + n0 + wn;
#pragma unroll
                for (int ni = 0; ni < 4; ni++) {
                    float g = accg[mi][ni][rr];
                    float u = accu[mi][ni][rr];
                    float h = (g / (1.f + expf(-g))) * u;
                    H[base + ni * 16 + lr] = f2bf(h);
                }
            }
        }
    }
}

// ---------------- GEMM2: H @ Wd -> Y bf16 (unweighted, no atomics) ----------
__global__ __launch_bounds__(256, 2)
void k_gemm2(const u16* __restrict__ H, const u16* __restrict__ wdt,
             const u16* __restrict__ wsdt, const int* __restrict__ counts,
             const int* __restrict__ offs, u16* __restrict__ Y) {
    int bx = blockIdx.x;
    int job = bx >> 7;
    int mt = (bx >> 3) & 15;
    int nt = bx & 7;
    int jcnt = counts[job];
    int m0 = mt << 7;
    if (m0 >= jcnt) return;
    int joff = offs[job];
    int n0 = nt << 7;
    const u16* Bt = (job < 8) ? (wdt + (size_t)job * 1048576) : wsdt;

    __shared__ __attribute__((aligned(128))) u16 As[4096];
    __shared__ __attribute__((aligned(128))) u16 Bs[4096];

    int t = threadIdx.x;
    int wave = t >> 6, lane = t & 63;
    int ch = (lane & 3) * 8;
    int r0 = (wave * 2 + 0) * 16 + (lane >> 2);
    int r1 = (wave * 2 + 1) * 16 + (lane >> 2);
    const u16* a0 = H + (size_t)(joff + m0 + r0) * 1024 + ch;
    const u16* a1 = H + (size_t)(joff + m0 + r1) * 1024 + ch;
    const u16* bB = Bt + (size_t)wave * 8192 + (size_t)(n0 + lane) * 8;
    u16* lA0 = As + (wave * 2 + 0) * 512;  u16* lA1 = As + (wave * 2 + 1) * 512;
    u16* lBa = Bs + wave * 1024;           u16* lBb = Bs + wave * 1024 + 512;

    int wm = (wave >> 1) << 6, wn = (wave & 1) << 6;
    int quad = lane >> 4, lr = lane & 15;

    f32x4 acc[4][4];
    f32x4 zz = {0.f, 0.f, 0.f, 0.f};
#pragma unroll
    for (int i = 0; i < 4; i++)
#pragma unroll
        for (int j = 0; j < 4; j++) acc[i][j] = zz;

    for (int k0 = 0; k0 < 1024; k0 += 32) {
        size_t koff = (size_t)k0 * 1024;
        GLDS16(a0 + k0, lA0);    GLDS16(a1 + k0, lA1);
        GLDS16(bB + koff, lBa);  GLDS16(bB + koff + 512, lBb);
        __syncthreads();
        short8 af[4], bf[4];
#pragma unroll
        for (int i = 0; i < 4; i++) {
            af[i] = *(const short8*)(As + (wm + i * 16 + lr) * 32 + quad * 8);
            bf[i] = *(const short8*)(Bs + quad * 1024 + (wn + i * 16 + lr) * 8);
        }
#pragma unroll
        for (int mi = 0; mi < 4; mi++)
#pragma unroll
            for (int ni = 0; ni < 4; ni++)
                acc[mi][ni] = __builtin_amdgcn_mfma_f32_16x16x32_bf16(af[mi], bf[ni], acc[mi][ni], 0, 0, 0);
        __syncthreads();
    }
#pragma unroll
    for (int mi = 0; mi < 4; mi++) {
        int rowb = m0 + wm + mi * 16 + quad * 4;
#pragma unroll
        for (int rr = 0; rr < 4; rr++) {
            int row = rowb + rr;
            if (row < jcnt) {
                u16* yrow = Y + (size_t)(joff + row) * 1024 + n0 + wn;
#pragma unroll
                for (int ni = 0; ni < 4; ni++)
                    yrow[ni * 16 + lr] = f2bf(acc[mi][ni][rr]);
            }
        }
    }
}

// ---------------- combine: out[n] = w0*Y[s0] + w1*Y[s1] + Y[4096+n] ---------
__global__ void k_combine(const u16* __restrict__ Y, const int* __restrict__ slots,
                          const float* __restrict__ tw, float* __restrict__ out) {
    int n = blockIdx.x;
    int d = threadIdx.x;
    int s0 = slots[n * 2], s1 = slots[n * 2 + 1];
    float w0 = tw[n * 2], w1 = tw[n * 2 + 1];
    u16x4 y0 = ((const u16x4*)(Y + (size_t)s0 * 1024))[d];
    u16x4 y1 = ((const u16x4*)(Y + (size_t)s1 * 1024))[d];
    u16x4 ys = ((const u16x4*)(Y + (size_t)(4096 + n) * 1024))[d];
    f32x4 r;
    r.x = w0 * bf2f(y0.x) + w1 * bf2f(y1.x) + bf2f(ys.x);
    r.y = w0 * bf2f(y0.y) + w1 * bf2f(y1.y) + bf2f(ys.y);
    r.z = w0 * bf2f(y0.z) + w1 * bf2f(y1.z) + bf2f(ys.z);
    r.w = w0 * bf2f(y0.w) + w1 * bf2f(y1.w) + bf2f(ys.w);
    ((f32x4*)(out + (size_t)n * 1024))[d] = r;
}

extern "C" void kernel_launch(void* const* d_in, const int* in_sizes, int n_in,
                              void* d_out, int out_size, void* d_ws, size_t ws_size,
                              hipStream_t stream) {
    const float* x     = (const float*)d_in[0];
    const float* wgate = (const float*)d_in[1];
    const float* wg    = (const float*)d_in[2];
    const float* wu    = (const float*)d_in[3];
    const float* wd    = (const float*)d_in[4];
    const float* wsg   = (const float*)d_in[5];
    const float* wsu   = (const float*)d_in[6];
    const float* wsd   = (const float*)d_in[7];
    float* out = (float*)d_out;

    char* ws = (char*)d_ws;
    u16*   xb    = (u16*)(ws + 0);           // 4 MB
    u16*   wgt   = (u16*)(ws + 4194304);     // 16 MB
    u16*   wut   = (u16*)(ws + 20971520);    // 16 MB
    u16*   wdt   = (u16*)(ws + 37748736);    // 16 MB
    u16*   wsgt  = (u16*)(ws + 54525952);    // 2 MB
    u16*   wsut  = (u16*)(ws + 56623104);    // 2 MB
    u16*   wsdt  = (u16*)(ws + 58720256);    // 2 MB
    u16*   H     = (u16*)(ws + 60817408);    // 12 MB
    // Y (bf16) overlays wgt (dead after gemm1; gemm2 runs strictly after)
    u16*   Y     = (u16*)(ws + 4194304);     // 12.58 MB
    int*   tidx  = (int*)(ws + 73400320);
    float* tw    = (float*)(ws + 73416704);
    int*   tlist = (int*)(ws + 73433088);
    int*   slots = (int*)(ws + 73457664);
    int*   counts= (int*)(ws + 73474048);
    int*   offs  = (int*)(ws + 73474112);
    int*   curs  = (int*)(ws + 73474176);
    float* Pp    = (float*)(ws + 73474304);  // 512*8 f32 = 16 KB
    int*   Cp    = (int*)(ws + 73490688);    // 512*8 i32 = 16 KB

    k_front<<<2816, 256, 0, stream>>>(wg, wu, wsg, wsu, wgt, wut, wsgt, wsut,
                                      x, wgate, xb, tidx, tw, Pp, Cp, tlist, curs);
    k_scatter<<<8, 256, 0, stream>>>(tidx, Pp, Cp, curs, tlist, slots,
                                     out, counts, offs);
    k_gemm1<<<2304, 256, 0, stream>>>(xb, wgt, wut, wsgt, wsut, tlist, counts, offs,
                                      H, wd, wsd, wdt, wsdt);
    k_gemm2<<<1152, 256, 0, stream>>>(H, wdt, wsdt, counts, offs, Y);
    k_combine<<<2048, 256, 0, stream>>>(Y, slots, tw, out);
}

// Round 3
// 260.884 us; speedup vs baseline: 1.0271x; 1.0135x over previous
//
#include <hip/hip_runtime.h>
#include <math.h>

typedef unsigned short u16;
typedef __attribute__((ext_vector_type(8))) short short8;
typedef __attribute__((ext_vector_type(4))) float f32x4;
typedef __attribute__((ext_vector_type(4))) unsigned short u16x4;
typedef __attribute__((ext_vector_type(8))) unsigned short u16x8;

#define N_TOK 2048
#define DIM 1024
#define OUT_ELEMS 2097152   // N_TOK * DIM

#define GLDS16(gp, lp) __builtin_amdgcn_global_load_lds( \
    (const __attribute__((address_space(1))) unsigned int*)(gp), \
    (__attribute__((address_space(3))) unsigned int*)(lp), 16, 0, 0)

__device__ __forceinline__ u16 f2bf(float f) {
    union { float f; unsigned u; } v; v.f = f;
    unsigned r = (v.u + 0x7FFFu + ((v.u >> 16) & 1u)) >> 16;
    return (u16)r;
}
__device__ __forceinline__ float bf2f(u16 h) {
    union { unsigned u; float f; } v; v.u = ((unsigned)h) << 16;
    return v.f;
}

// ---- cvt of one 8-row k-chunk: fp32 [8][1024] -> bf16 W'[n][8k] (16KB) ----
__device__ __forceinline__ void cvt_chunk(const float* __restrict__ src,
                                          u16* __restrict__ dst, int chunk,
                                          char* smem, int t) {
    float* tile = (float*)smem;                          // [8][1024] f32 = 32KB
    const char* gsrc = (const char*)(src + (size_t)chunk * 8192);
    u16* dchunk = dst + (size_t)chunk * 8192;            // 16KB contiguous out
    int w = t >> 6, l = t & 63;
#pragma unroll
    for (int j = 0; j < 8; j++) {
        int idx = w * 8 + j;                             // 1KB unit, 0..31
        GLDS16(gsrc + idx * 1024 + l * 16, smem + idx * 1024);
    }
    __syncthreads();
    int n0 = (t & 63) * 4 + (t >> 6) * 256;              // 4 consecutive n per thread
    f32x4 v[8];
#pragma unroll
    for (int k = 0; k < 8; k++)
        v[k] = *(const f32x4*)(tile + k * 1024 + n0);    // bank = n%32: conflict-free
#pragma unroll
    for (int i = 0; i < 4; i++) {
        u16x8 o;
#pragma unroll
        for (int k = 0; k < 8; k++) o[k] = f2bf(v[k][i]);
        *(u16x8*)(dchunk + (size_t)(n0 + i) * 8) = o;    // 16B aligned, coalesced
    }
}

// ---------------- k_front: cvt(gate/up, 18 mats) + router, one launch -------
__global__ __launch_bounds__(256)
void k_front(const float* __restrict__ wg, const float* __restrict__ wu,
             const float* __restrict__ wsg, const float* __restrict__ wsu,
             u16* __restrict__ wgt, u16* __restrict__ wut,
             u16* __restrict__ wsgt, u16* __restrict__ wsut,
             const float* __restrict__ x, const float* __restrict__ wgate,
             u16* __restrict__ xb, int* __restrict__ tidx, float* __restrict__ tw,
             float* __restrict__ Pp, int* __restrict__ Cp,
             int* __restrict__ tlist, int* __restrict__ curs) {
    __shared__ __attribute__((aligned(128))) char smem[32768];
    int bx = blockIdx.x;
    int t = threadIdx.x;
    if (bx < 2304) {                                     // ---- cvt role ----
        int mat = bx >> 7, chunk = bx & 127;
        const float* src; u16* dst;
        if      (mat <  8) { src = wg + (size_t)mat * 1048576;       dst = wgt + (size_t)mat * 1048576; }
        else if (mat < 16) { src = wu + (size_t)(mat - 8) * 1048576; dst = wut + (size_t)(mat - 8) * 1048576; }
        else if (mat == 16){ src = wsg; dst = wsgt; }
        else               { src = wsu; dst = wsut; }
        cvt_chunk(src, dst, chunk, smem, t);
        return;
    }
    // ---- router role: block b handles tokens 4b..4b+3, one per wave ----
    int b = bx - 2304;                                   // 0..511
    float* sP = (float*)smem;
    int*   sC = (int*)(smem + 64);
    if (t < 8) { sP[t] = 0.f; sC[t] = 0; }
    if (b == 0 && t < 16) curs[t] = 0;                   // safe: scatter runs next launch
    __syncthreads();
    int wave = t >> 6;
    int lane = t & 63;
    int n = b * 4 + wave;
    const float* xr = x + (size_t)n * DIM;
    u16* xbr = xb + (size_t)n * DIM;
    float acc[8] = {0.f,0.f,0.f,0.f,0.f,0.f,0.f,0.f};
#pragma unroll
    for (int i = 0; i < 16; i++) {
        int d = lane + i * 64;
        float xv = xr[d];
        xbr[d] = f2bf(xv);
        const float* wr = wgate + d * 8;
#pragma unroll
        for (int e = 0; e < 8; e++) acc[e] += xv * wr[e];
    }
#pragma unroll
    for (int off = 32; off; off >>= 1) {
#pragma unroll
        for (int e = 0; e < 8; e++) acc[e] += __shfl_xor(acc[e], off);
    }
    if (lane == 0) {
        tlist[4096 + n] = n;                             // shared-expert token list
        float mx = acc[0];
#pragma unroll
        for (int e = 1; e < 8; e++) mx = fmaxf(mx, acc[e]);
        float p[8], s = 0.f;
#pragma unroll
        for (int e = 0; e < 8; e++) { p[e] = expf(acc[e] - mx); s += p[e]; }
        float inv = 1.f / s;
#pragma unroll
        for (int e = 0; e < 8; e++) atomicAdd(&sP[e], p[e] * inv);
        int i0 = 0; float b0 = acc[0];
#pragma unroll
        for (int e = 1; e < 8; e++) if (acc[e] > b0) { b0 = acc[e]; i0 = e; }
        int i1 = -1; float b1 = -3.4e38f;
#pragma unroll
        for (int e = 0; e < 8; e++) if (e != i0 && acc[e] > b1) { b1 = acc[e]; i1 = e; }
        float w0 = 1.f / (1.f + expf(b1 - b0));
        tidx[n * 2] = i0; tidx[n * 2 + 1] = i1;
        tw[n * 2] = w0;   tw[n * 2 + 1] = 1.f - w0;
        atomicAdd(&sC[i0], 1);
        atomicAdd(&sC[i1], 1);
    }
    __syncthreads();
    if (t < 8) { Pp[b * 8 + t] = sP[t]; Cp[b * 8 + t] = sC[t]; }   // per-block partials
}

// -------- scatter: reduce partials, aux loss, offs, slot assignment ---------
__global__ void k_scatter(const int* __restrict__ tidx, const float* __restrict__ Pp,
                          const int* __restrict__ Cp, int* __restrict__ curs,
                          int* __restrict__ tlist, int* __restrict__ slots,
                          float* __restrict__ out, int* __restrict__ counts,
                          int* __restrict__ offs) {
    __shared__ int   s_off[8];
    __shared__ int   sCnt[8];
    __shared__ float sPs[8];
    __shared__ int   redC[256];
    __shared__ float redP[256];
    int t = threadIdx.x;
    int e = t & 7, g = t >> 3;                           // 32 groups per expert
    int cs = 0; float ps = 0.f;
#pragma unroll
    for (int j = 0; j < 16; j++) {
        int b = g + j * 32;
        cs += Cp[b * 8 + e];
        ps += Pp[b * 8 + e];
    }
    redC[t] = cs; redP[t] = ps;
    __syncthreads();
    if (t < 8) {
        int c = 0; float p = 0.f;
        for (int g2 = 0; g2 < 32; g2++) { c += redC[g2 * 8 + t]; p += redP[g2 * 8 + t]; }
        sCnt[t] = c; sPs[t] = p;
    }
    __syncthreads();
    if (t == 0) {
        int o = 0;
        for (int e2 = 0; e2 < 8; e2++) { s_off[e2] = o; o += sCnt[e2]; }
    }
    __syncthreads();
    if (blockIdx.x == 0 && t == 0) {
        float aux = 0.f;
        for (int e2 = 0; e2 < 8; e2++) {
            aux += (float)sCnt[e2] * sPs[e2];
            offs[e2] = s_off[e2]; counts[e2] = sCnt[e2];
        }
        out[OUT_ELEMS] = 8.f * aux / ((float)N_TOK * (float)N_TOK);
        offs[8] = 4096; counts[8] = 2048;
    }
    int n = blockIdx.x * 256 + t;
    if (n < N_TOK) {
#pragma unroll
        for (int k = 0; k < 2; k++) {
            int ee = tidx[n * 2 + k];
            int p = atomicAdd(&curs[ee], 1);
            int sl = s_off[ee] + p;
            tlist[sl] = n;
            slots[n * 2 + k] = sl;
        }
    }
}

// -------- GEMM1: 2-phase double-buffered pipeline (+fused cvt_d role) -------
// Per k-step: issue STAGE(next buf) FIRST, then ds_read+MFMA current, then one
// __syncthreads (vmcnt(0)+barrier). Prefetch latency hides under compute.
__global__ __launch_bounds__(256, 2)
void k_gemm1(const u16* __restrict__ xb, const u16* __restrict__ wgt,
             const u16* __restrict__ wut, const u16* __restrict__ wsgt,
             const u16* __restrict__ wsut, const int* __restrict__ tlist,
             const int* __restrict__ counts, const int* __restrict__ offs,
             u16* __restrict__ H,
             const float* __restrict__ wd, const float* __restrict__ wsd,
             u16* __restrict__ wdt, u16* __restrict__ wsdt) {
    __shared__ __attribute__((aligned(128))) char smem[49152];   // 2 x 24KB
    int bx = blockIdx.x;
    int t = threadIdx.x;
    if (bx < 1152) {                                     // ---- cvt_d role ----
        int mat = bx >> 7, chunk = bx & 127;
        const float* src = (mat < 8) ? (wd + (size_t)mat * 1048576) : wsd;
        u16* dst = (mat < 8) ? (wdt + (size_t)mat * 1048576) : wsdt;
        cvt_chunk(src, dst, chunk, smem, t);
        return;
    }
    int bg = bx - 1152;
    int job = bg >> 7;
    int mt = (bg >> 3) & 15;
    int nt = bg & 7;
    int jcnt = counts[job];
    int m0 = mt << 7;
    if (m0 >= jcnt) return;
    int joff = offs[job];
    int n0 = nt << 7;
    const u16* Bg = (job < 8) ? (wgt + (size_t)job * 1048576) : wsgt;
    const u16* Bu = (job < 8) ? (wut + (size_t)job * 1048576) : wsut;

    int wave = t >> 6, lane = t & 63;
    int ch = (lane & 3) * 8;
    int r0 = (wave * 2 + 0) * 16 + (lane >> 2);
    int r1 = (wave * 2 + 1) * 16 + (lane >> 2);
    int tok0 = tlist[joff + m0 + r0];
    int tok1 = tlist[joff + m0 + r1];
    const u16* a0 = xb + (size_t)tok0 * 1024 + ch;
    const u16* a1 = xb + (size_t)tok1 * 1024 + ch;
    const u16* gB = Bg + (size_t)wave * 8192 + (size_t)(n0 + lane) * 8;
    const u16* uB = Bu + (size_t)wave * 8192 + (size_t)(n0 + lane) * 8;

    int wm = (wave >> 1) << 6, wn = (wave & 1) << 6;
    int quad = lane >> 4, lr = lane & 15;

    f32x4 accg[4][4], accu[4][4];
    f32x4 zz = {0.f, 0.f, 0.f, 0.f};
#pragma unroll
    for (int i = 0; i < 4; i++)
#pragma unroll
        for (int j = 0; j < 4; j++) { accg[i][j] = zz; accu[i][j] = zz; }

    // stage k-step s into buffer b (6 x GLDS16 per thread)
#define STAGE1(b_, s_) do { \
        char* bb = smem + (b_) * 24576; \
        u16* As_  = (u16*)bb; \
        u16* Bgs_ = (u16*)(bb + 8192); \
        u16* Bus_ = (u16*)(bb + 16384); \
        int k0_ = (s_) * 32; \
        size_t koff_ = (size_t)k0_ * 1024; \
        GLDS16(a0 + k0_, As_ + (wave * 2 + 0) * 512); \
        GLDS16(a1 + k0_, As_ + (wave * 2 + 1) * 512); \
        GLDS16(gB + koff_,       Bgs_ + wave * 1024); \
        GLDS16(gB + koff_ + 512, Bgs_ + wave * 1024 + 512); \
        GLDS16(uB + koff_,       Bus_ + wave * 1024); \
        GLDS16(uB + koff_ + 512, Bus_ + wave * 1024 + 512); \
    } while (0)

    STAGE1(0, 0);
    __syncthreads();                                     // buffer 0 ready
    for (int s = 0; s < 32; s++) {
        int cur = s & 1;
        if (s < 31) STAGE1(cur ^ 1, s + 1);              // prefetch next k-step
        const char* cb = smem + cur * 24576;
        const u16* Asr = (const u16*)cb;
        const u16* Bgr = (const u16*)(cb + 8192);
        const u16* Bur = (const u16*)(cb + 16384);
        short8 af[4], bgf[4], buf[4];
#pragma unroll
        for (int i = 0; i < 4; i++) {
            int nrow = wn + i * 16 + lr;
            af[i]  = *(const short8*)(Asr + (wm + i * 16 + lr) * 32 + quad * 8);
            bgf[i] = *(const short8*)(Bgr + quad * 1024 + nrow * 8);
            buf[i] = *(const short8*)(Bur + quad * 1024 + nrow * 8);
        }
#pragma unroll
        for (int mi = 0; mi < 4; mi++)
#pragma unroll
            for (int ni = 0; ni < 4; ni++) {
                accg[mi][ni] = __builtin_amdgcn_mfma_f32_16x16x32_bf16(af[mi], bgf[ni], accg[mi][ni], 0, 0, 0);
                accu[mi][ni] = __builtin_amdgcn_mfma_f32_16x16x32_bf16(af[mi], buf[ni], accu[mi][ni], 0, 0, 0);
            }
        __syncthreads();                                 // vmcnt(0)+barrier: next buf ready
    }
#undef STAGE1
#pragma unroll
    for (int mi = 0; mi < 4; mi++) {
        int rowb = m0 + wm + mi * 16 + quad * 4;
#pragma unroll
        for (int rr = 0; rr < 4; rr++) {
            int row = rowb + rr;
            if (row < jcnt) {
                size_t base = (size_t)(joff + row) * 1024 + n0 + wn;
#pragma unroll
                for (int ni = 0; ni < 4; ni++) {
                    float g = accg[mi][ni][rr];
                    float u = accu[mi][ni][rr];
                    float h = (g / (1.f + expf(-g))) * u;
                    H[base + ni * 16 + lr] = f2bf(h);
                }
            }
        }
    }
}

// -------- GEMM2: H @ Wd -> Y bf16, same 2-phase double-buffered pipeline ----
__global__ __launch_bounds__(256, 2)
void k_gemm2(const u16* __restrict__ H, const u16* __restrict__ wdt,
             const u16* __restrict__ wsdt, const int* __restrict__ counts,
             const int* __restrict__ offs, u16* __restrict__ Y) {
    __shared__ __attribute__((aligned(128))) char smem[32768];   // 2 x 16KB
    int bx = blockIdx.x;
    int job = bx >> 7;
    int mt = (bx >> 3) & 15;
    int nt = bx & 7;
    int jcnt = counts[job];
    int m0 = mt << 7;
    if (m0 >= jcnt) return;
    int joff = offs[job];
    int n0 = nt << 7;
    const u16* Bt = (job < 8) ? (wdt + (size_t)job * 1048576) : wsdt;

    int t = threadIdx.x;
    int wave = t >> 6, lane = t & 63;
    int ch = (lane & 3) * 8;
    int r0 = (wave * 2 + 0) * 16 + (lane >> 2);
    int r1 = (wave * 2 + 1) * 16 + (lane >> 2);
    const u16* a0 = H + (size_t)(joff + m0 + r0) * 1024 + ch;
    const u16* a1 = H + (size_t)(joff + m0 + r1) * 1024 + ch;
    const u16* bB = Bt + (size_t)wave * 8192 + (size_t)(n0 + lane) * 8;

    int wm = (wave >> 1) << 6, wn = (wave & 1) << 6;
    int quad = lane >> 4, lr = lane & 15;

    f32x4 acc[4][4];
    f32x4 zz = {0.f, 0.f, 0.f, 0.f};
#pragma unroll
    for (int i = 0; i < 4; i++)
#pragma unroll
        for (int j = 0; j < 4; j++) acc[i][j] = zz;

#define STAGE2(b_, s_) do { \
        char* bb = smem + (b_) * 16384; \
        u16* As_ = (u16*)bb; \
        u16* Bs_ = (u16*)(bb + 8192); \
        int k0_ = (s_) * 32; \
        size_t koff_ = (size_t)k0_ * 1024; \
        GLDS16(a0 + k0_, As_ + (wave * 2 + 0) * 512); \
        GLDS16(a1 + k0_, As_ + (wave * 2 + 1) * 512); \
        GLDS16(bB + koff_,       Bs_ + wave * 1024); \
        GLDS16(bB + koff_ + 512, Bs_ + wave * 1024 + 512); \
    } while (0)

    STAGE2(0, 0);
    __syncthreads();
    for (int s = 0; s < 32; s++) {
        int cur = s & 1;
        if (s < 31) STAGE2(cur ^ 1, s + 1);
        const char* cb = smem + cur * 16384;
        const u16* Asr = (const u16*)cb;
        const u16* Bsr = (const u16*)(cb + 8192);
        short8 af[4], bf[4];
#pragma unroll
        for (int i = 0; i < 4; i++) {
            af[i] = *(const short8*)(Asr + (wm + i * 16 + lr) * 32 + quad * 8);
            bf[i] = *(const short8*)(Bsr + quad * 1024 + (wn + i * 16 + lr) * 8);
        }
#pragma unroll
        for (int mi = 0; mi < 4; mi++)
#pragma unroll
            for (int ni = 0; ni < 4; ni++)
                acc[mi][ni] = __builtin_amdgcn_mfma_f32_16x16x32_bf16(af[mi], bf[ni], acc[mi][ni], 0, 0, 0);
        __syncthreads();
    }
#undef STAGE2
#pragma unroll
    for (int mi = 0; mi < 4; mi++) {
        int rowb = m0 + wm + mi * 16 + quad * 4;
#pragma unroll
        for (int rr = 0; rr < 4; rr++) {
            int row = rowb + rr;
            if (row < jcnt) {
                u16* yrow = Y + (size_t)(joff + row) * 1024 + n0 + wn;
#pragma unroll
                for (int ni = 0; ni < 4; ni++)
                    yrow[ni * 16 + lr] = f2bf(acc[mi][ni][rr]);
            }
        }
    }
}

// ---------------- combine: out[n] = w0*Y[s0] + w1*Y[s1] + Y[4096+n] ---------
__global__ void k_combine(const u16* __restrict__ Y, const int* __restrict__ slots,
                          const float* __restrict__ tw, float* __restrict__ out) {
    int n = blockIdx.x;
    int d = threadIdx.x;
    int s0 = slots[n * 2], s1 = slots[n * 2 + 1];
    float w0 = tw[n * 2], w1 = tw[n * 2 + 1];
    u16x4 y0 = ((const u16x4*)(Y + (size_t)s0 * 1024))[d];
    u16x4 y1 = ((const u16x4*)(Y + (size_t)s1 * 1024))[d];
    u16x4 ys = ((const u16x4*)(Y + (size_t)(4096 + n) * 1024))[d];
    f32x4 r;
    r.x = w0 * bf2f(y0.x) + w1 * bf2f(y1.x) + bf2f(ys.x);
    r.y = w0 * bf2f(y0.y) + w1 * bf2f(y1.y) + bf2f(ys.y);
    r.z = w0 * bf2f(y0.z) + w1 * bf2f(y1.z) + bf2f(ys.z);
    r.w = w0 * bf2f(y0.w) + w1 * bf2f(y1.w) + bf2f(ys.w);
    ((f32x4*)(out + (size_t)n * 1024))[d] = r;
}

extern "C" void kernel_launch(void* const* d_in, const int* in_sizes, int n_in,
                              void* d_out, int out_size, void* d_ws, size_t ws_size,
                              hipStream_t stream) {
    const float* x     = (const float*)d_in[0];
    const float* wgate = (const float*)d_in[1];
    const float* wg    = (const float*)d_in[2];
    const float* wu    = (const float*)d_in[3];
    const float* wd    = (const float*)d_in[4];
    const float* wsg   = (const float*)d_in[5];
    const float* wsu   = (const float*)d_in[6];
    const float* wsd   = (const float*)d_in[7];
    float* out = (float*)d_out;

    char* ws = (char*)d_ws;
    u16*   xb    = (u16*)(ws + 0);           // 4 MB
    u16*   wgt   = (u16*)(ws + 4194304);     // 16 MB
    u16*   wut   = (u16*)(ws + 20971520);    // 16 MB
    u16*   wdt   = (u16*)(ws + 37748736);    // 16 MB
    u16*   wsgt  = (u16*)(ws + 54525952);    // 2 MB
    u16*   wsut  = (u16*)(ws + 56623104);    // 2 MB
    u16*   wsdt  = (u16*)(ws + 58720256);    // 2 MB
    u16*   H     = (u16*)(ws + 60817408);    // 12 MB
    // Y (bf16) overlays wgt (dead after gemm1; gemm2 runs strictly after)
    u16*   Y     = (u16*)(ws + 4194304);     // 12.58 MB
    int*   tidx  = (int*)(ws + 73400320);
    float* tw    = (float*)(ws + 73416704);
    int*   tlist = (int*)(ws + 73433088);
    int*   slots = (int*)(ws + 73457664);
    int*   counts= (int*)(ws + 73474048);
    int*   offs  = (int*)(ws + 73474112);
    int*   curs  = (int*)(ws + 73474176);
    float* Pp    = (float*)(ws + 73474304);  // 512*8 f32 = 16 KB
    int*   Cp    = (int*)(ws + 73490688);    // 512*8 i32 = 16 KB

    k_front<<<2816, 256, 0, stream>>>(wg, wu, wsg, wsu, wgt, wut, wsgt, wsut,
                                      x, wgate, xb, tidx, tw, Pp, Cp, tlist, curs);
    k_scatter<<<8, 256, 0, stream>>>(tidx, Pp, Cp, curs, tlist, slots,
                                     out, counts, offs);
    k_gemm1<<<2304, 256, 0, stream>>>(xb, wgt, wut, wsgt, wsut, tlist, counts, offs,
                                      H, wd, wsd, wdt, wsdt);
    k_gemm2<<<1152, 256, 0, stream>>>(H, wdt, wsdt, counts, offs, Y);
    k_combine<<<2048, 256, 0, stream>>>(Y, slots, tw, out);
}